// Round 5
// baseline (73.020 us; speedup 1.0000x reference)
//
#include <hip/hip_runtime.h>
#include <hip/hip_bf16.h>
#include <math.h>

// out[b,i,j,o] = lrelu( sum_k pe[d_k(b,i,j)] @ W[k*H:(k+1)*H, o] + b[o] )
// Pipeline: (0) transpose W -> Wt[k][o][h] for contiguous column reads,
// (1) Y[k][r][o] = pe[r,:]@W_k[:,o] (+bias in k==0) in fp32, stored bf16
//     (2.1 MB table, L2-resident), (2) gather-add 4 rows + lrelu, fp32 accum,
//     nontemporal fp32 stores (write-bound, 134 MB).

typedef float f32x4 __attribute__((ext_vector_type(4)));

__device__ __forceinline__ float lrelu(float x) {
    return fmaxf(x, 0.01f * x);
}

__device__ __forceinline__ float bfu32_lo(unsigned int v) {
    union { unsigned int i; float f; } c; c.i = v << 16; return c.f;
}
__device__ __forceinline__ float bfu32_hi(unsigned int v) {
    union { unsigned int i; float f; } c; c.i = v & 0xffff0000u; return c.f;
}

// ------------- Kernel 0: W[k*H + h][o] -> Wt[k*H + o][h]  (H=256) -------------
// 256 blocks of 256 threads; 32x32 LDS tile, coalesced both sides.
__global__ __launch_bounds__(256) void transpose_W(const float* __restrict__ W,
                                                   float* __restrict__ Wt) {
    const int k  = blockIdx.x >> 6;          // 64 tiles per k
    const int tt = blockIdx.x & 63;
    const int h0 = (tt >> 3) << 5;
    const int o0 = (tt & 7) << 5;
    const int tx = threadIdx.x & 31;
    const int ty = threadIdx.x >> 5;         // 0..7

    __shared__ float tile[32][33];

#pragma unroll
    for (int m = 0; m < 4; ++m)
        tile[ty + 8 * m][tx] = W[((size_t)(k * 256 + h0 + ty + 8 * m) << 8) + o0 + tx];
    __syncthreads();
#pragma unroll
    for (int m = 0; m < 4; ++m)
        Wt[((size_t)(k * 256 + o0 + ty + 8 * m) << 8) + h0 + tx] = tile[tx][ty + 8 * m];
}

// ------------- Kernel 1: Y precompute, 4 rows/thread, Wt contiguous -----------
// grid = 4 * ceil(NPE/4); block = 256 (thread = output col o).
__global__ __launch_bounds__(256) void precompute_Yt(
        const float* __restrict__ pe,
        const float* __restrict__ Wt,
        const float* __restrict__ bias,
        __hip_bfloat16* __restrict__ Y,
        int NPE) {
    const int ntile = (NPE + 3) >> 2;
    const int k  = blockIdx.x / ntile;
    const int r0 = (blockIdx.x % ntile) << 2;
    const int o  = threadIdx.x;

    const float* __restrict__ wrow = Wt + ((size_t)(k * 256 + o) << 8);
    const float* __restrict__ p0 = pe + ((size_t)min(r0 + 0, NPE - 1) << 8);
    const float* __restrict__ p1 = pe + ((size_t)min(r0 + 1, NPE - 1) << 8);
    const float* __restrict__ p2 = pe + ((size_t)min(r0 + 2, NPE - 1) << 8);
    const float* __restrict__ p3 = pe + ((size_t)min(r0 + 3, NPE - 1) << 8);

    f32x4 a0 = 0.f, a1 = 0.f, a2 = 0.f, a3 = 0.f;

#pragma unroll 2
    for (int h = 0; h < 256; h += 8) {
        const f32x4 wA = *reinterpret_cast<const f32x4*>(wrow + h);
        const f32x4 wB = *reinterpret_cast<const f32x4*>(wrow + h + 4);
        a0 += *reinterpret_cast<const f32x4*>(p0 + h) * wA;
        a0 += *reinterpret_cast<const f32x4*>(p0 + h + 4) * wB;
        a1 += *reinterpret_cast<const f32x4*>(p1 + h) * wA;
        a1 += *reinterpret_cast<const f32x4*>(p1 + h + 4) * wB;
        a2 += *reinterpret_cast<const f32x4*>(p2 + h) * wA;
        a2 += *reinterpret_cast<const f32x4*>(p2 + h + 4) * wB;
        a3 += *reinterpret_cast<const f32x4*>(p3 + h) * wA;
        a3 += *reinterpret_cast<const f32x4*>(p3 + h + 4) * wB;
    }

    const float bv = (k == 0) ? bias[o] : 0.f;
    float s[4];
    s[0] = a0.x + a0.y + a0.z + a0.w;
    s[1] = a1.x + a1.y + a1.z + a1.w;
    s[2] = a2.x + a2.y + a2.z + a2.w;
    s[3] = a3.x + a3.y + a3.z + a3.w;
#pragma unroll
    for (int r = 0; r < 4; ++r) {
        const int rr = r0 + r;
        if (rr < NPE)
            Y[((size_t)k * NPE + rr) * 256 + o] = __float2bfloat16(s[r] + bv);
    }
}

// ------------- Kernel 2: gather-add + lrelu, 2 j's per lane --------------------
// block = 256 = 4 waves; wave w handles j = jbase + 2w + {0,1}; 64 lanes/row.
__global__ __launch_bounds__(256) void gather2(
        const int* __restrict__ pos_s,
        const int* __restrict__ pos_e,
        const __hip_bfloat16* __restrict__ Y,
        float* __restrict__ out,
        int S, int ML, int NPE) {
    const int t  = threadIdx.x;
    const int w  = t >> 6;
    const int ln = t & 63;
    const int S8 = S >> 3;

    const int blk   = blockIdx.x;
    const int jbase = (blk % S8) << 3;
    const int i     = (blk / S8) % S;
    const int bb    = blk / (S8 * S);
    const int j0    = jbase + (w << 1);
    const int j1    = j0 + 1;

    const int si = pos_s[bb * S + i];
    const int ei = pos_e[bb * S + i];
    const int sj0 = pos_s[bb * S + j0];
    const int ej0 = pos_e[bb * S + j0];
    const int sj1 = pos_s[bb * S + j1];
    const int ej1 = pos_e[bb * S + j1];

    const uint2* __restrict__ Yv = reinterpret_cast<const uint2*>(Y);
    // row r (global, includes k*NPE) -> 64 uint2; lane ln
#define YIDX(r) (((size_t)(r) << 6) + ln)
    const int a0 = 0 * NPE + si - sj0 + ML;
    const int a1 = 1 * NPE + si - ej0 + ML;
    const int a2 = 2 * NPE + ei - sj0 + ML;
    const int a3 = 3 * NPE + ei - ej0 + ML;
    const int b0 = 0 * NPE + si - sj1 + ML;
    const int b1 = 1 * NPE + si - ej1 + ML;
    const int b2 = 2 * NPE + ei - sj1 + ML;
    const int b3 = 3 * NPE + ei - ej1 + ML;

    const uint2 uA0 = Yv[YIDX(a0)], uA1 = Yv[YIDX(a1)],
                uA2 = Yv[YIDX(a2)], uA3 = Yv[YIDX(a3)];
    const uint2 uB0 = Yv[YIDX(b0)], uB1 = Yv[YIDX(b1)],
                uB2 = Yv[YIDX(b2)], uB3 = Yv[YIDX(b3)];
#undef YIDX

    f32x4 vA, vB;
    vA.x = lrelu(bfu32_lo(uA0.x) + bfu32_lo(uA1.x) + bfu32_lo(uA2.x) + bfu32_lo(uA3.x));
    vA.y = lrelu(bfu32_hi(uA0.x) + bfu32_hi(uA1.x) + bfu32_hi(uA2.x) + bfu32_hi(uA3.x));
    vA.z = lrelu(bfu32_lo(uA0.y) + bfu32_lo(uA1.y) + bfu32_lo(uA2.y) + bfu32_lo(uA3.y));
    vA.w = lrelu(bfu32_hi(uA0.y) + bfu32_hi(uA1.y) + bfu32_hi(uA2.y) + bfu32_hi(uA3.y));
    vB.x = lrelu(bfu32_lo(uB0.x) + bfu32_lo(uB1.x) + bfu32_lo(uB2.x) + bfu32_lo(uB3.x));
    vB.y = lrelu(bfu32_hi(uB0.x) + bfu32_hi(uB1.x) + bfu32_hi(uB2.x) + bfu32_hi(uB3.x));
    vB.z = lrelu(bfu32_lo(uB0.y) + bfu32_lo(uB1.y) + bfu32_lo(uB2.y) + bfu32_lo(uB3.y));
    vB.w = lrelu(bfu32_hi(uB0.y) + bfu32_hi(uB1.y) + bfu32_hi(uB2.y) + bfu32_hi(uB3.y));

    const size_t orow = ((size_t)bb * S + i) * S;
    f32x4* __restrict__ ov = reinterpret_cast<f32x4*>(out);
    __builtin_nontemporal_store(vA, &ov[((orow + j0) << 6) + ln]);
    __builtin_nontemporal_store(vB, &ov[((orow + j1) << 6) + ln]);
}

// ------------- Fallback A: precompute without Wt (if ws fits only Y) ----------
__global__ __launch_bounds__(256) void precompute_Y_noT(
        const float* __restrict__ pe,
        const float* __restrict__ W,
        const float* __restrict__ bias,
        __hip_bfloat16* __restrict__ Y,
        int NPE) {
    const int H = 256;
    const int ntile = (NPE + 7) >> 3;
    const int k  = blockIdx.x / ntile;
    const int r0 = (blockIdx.x % ntile) << 3;
    const int o  = threadIdx.x;
    const float* __restrict__ Wk = W + (size_t)k * H * H;

    int rows[8];
#pragma unroll
    for (int r = 0; r < 8; ++r) rows[r] = min(r0 + r, NPE - 1);

    float acc[8];
#pragma unroll
    for (int r = 0; r < 8; ++r) acc[r] = 0.f;

#pragma unroll 2
    for (int h = 0; h < 256; h += 4) {
        const float w0 = Wk[(h + 0) * H + o];
        const float w1 = Wk[(h + 1) * H + o];
        const float w2 = Wk[(h + 2) * H + o];
        const float w3 = Wk[(h + 3) * H + o];
#pragma unroll
        for (int r = 0; r < 8; ++r) {
            const f32x4 p = *reinterpret_cast<const f32x4*>(&pe[rows[r] * H + h]);
            acc[r] += p.x * w0 + p.y * w1 + p.z * w2 + p.w * w3;
        }
    }
    const float bv = (k == 0) ? bias[o] : 0.f;
#pragma unroll
    for (int r = 0; r < 8; ++r) {
        const int rr = r0 + r;
        if (rr < NPE)
            Y[((size_t)k * NPE + rr) * H + o] = __float2bfloat16(acc[r] + bv);
    }
}

// ------------- Fallback B: direct compute (ws too small) ----------------------
__global__ void direct_kernel(const int* __restrict__ pos_s,
                              const int* __restrict__ pos_e,
                              const float* __restrict__ pe,
                              const float* __restrict__ W,
                              const float* __restrict__ bias,
                              float* __restrict__ out,
                              int B, int S, int H, int ML) {
    const int blk = blockIdx.x;
    const int j   = blk % S;
    const int i   = (blk / S) % S;
    const int bb  = blk / (S * S);
    const int o   = threadIdx.x;

    const int si = pos_s[bb * S + i];
    const int ei = pos_e[bb * S + i];
    const int sj = pos_s[bb * S + j];
    const int ej = pos_e[bb * S + j];

    const int rss = si - sj + ML;
    const int rse = si - ej + ML;
    const int res = ei - sj + ML;
    const int ree = ei - ej + ML;

    float acc = bias[o];
    for (int h = 0; h < H; ++h) {
        acc += pe[rss * H + h] * W[(0 * H + h) * H + o];
        acc += pe[rse * H + h] * W[(1 * H + h) * H + o];
        acc += pe[res * H + h] * W[(2 * H + h) * H + o];
        acc += pe[ree * H + h] * W[(3 * H + h) * H + o];
    }
    out[(((size_t)bb * S + i) * S + j) * H + o] = lrelu(acc);
}

extern "C" void kernel_launch(void* const* d_in, const int* in_sizes, int n_in,
                              void* d_out, int out_size, void* d_ws, size_t ws_size,
                              hipStream_t stream) {
    const int*   pos_s = (const int*)d_in[0];
    const int*   pos_e = (const int*)d_in[1];
    const float* pe    = (const float*)d_in[2];
    const float* W     = (const float*)d_in[3];
    const float* bias  = (const float*)d_in[4];
    float*       out   = (float*)d_out;

    const int H   = in_sizes[4];                 // 256
    const int NPE = in_sizes[2] / H;             // 1025
    const int ML  = (NPE - 1) / 2;               // 512
    const int BS  = in_sizes[0];                 // B*S
    const int S   = (int)((long long)out_size / ((long long)BS * H)); // 256
    const int B   = BS / S;                      // 2

    const size_t ybytes  = (size_t)4 * NPE * 256 * sizeof(__hip_bfloat16); // 2.1 MB
    const size_t yal     = (ybytes + 255) & ~(size_t)255;
    const size_t wtbytes = (size_t)4 * 256 * 256 * sizeof(float);          // 1 MB

    if (H == 256 && (S & 7) == 0 && ws_size >= yal + wtbytes) {
        __hip_bfloat16* Y  = (__hip_bfloat16*)d_ws;
        float*          Wt = (float*)((char*)d_ws + yal);
        transpose_W<<<256, 256, 0, stream>>>(W, Wt);
        const int ntile = (NPE + 3) >> 2;
        precompute_Yt<<<4 * ntile, 256, 0, stream>>>(pe, Wt, bias, Y, NPE);
        const int nblk = B * S * (S >> 3);
        gather2<<<nblk, 256, 0, stream>>>(pos_s, pos_e, Y, out, S, ML, NPE);
    } else if (H == 256 && (S & 7) == 0 && ws_size >= ybytes) {
        __hip_bfloat16* Y = (__hip_bfloat16*)d_ws;
        const int ntile = (NPE + 7) >> 3;
        precompute_Y_noT<<<4 * ntile, 256, 0, stream>>>(pe, W, bias, Y, NPE);
        const int nblk = B * S * (S >> 3);
        gather2<<<nblk, 256, 0, stream>>>(pos_s, pos_e, Y, out, S, ML, NPE);
    } else {
        direct_kernel<<<B * S * S, H, 0, stream>>>(pos_s, pos_e, pe, W, bias, out,
                                                   B, S, H, ML);
    }
}

// Round 6
// 59.684 us; speedup vs baseline: 1.2234x; 1.2234x over previous
//
#include <hip/hip_runtime.h>
#include <hip/hip_bf16.h>
#include <math.h>

// out[b,i,j,o] = lrelu( sum_k pe[d_k(b,i,j)] @ W[k*H:(k+1)*H, o] + b[o] )
// (1) Y[k][r][o] = pe[r,:]@W_k[:,o] (+bias at k==0), fp32 math, bf16 store
//     (2.1 MB table -> L2-resident), W columns read coalesced (lane=o).
// (2) gather-add + lrelu: wave = 16 consecutive j's, pipelined (unroll 4),
//     4 x 8B table loads + 1 KB NT store per j.

typedef float f32x4 __attribute__((ext_vector_type(4)));

__device__ __forceinline__ float lrelu(float x) {
    return fmaxf(x, 0.01f * x);
}
__device__ __forceinline__ float bflo(unsigned int v) {
    union { unsigned int i; float f; } c; c.i = v << 16; return c.f;
}
__device__ __forceinline__ float bfhi(unsigned int v) {
    union { unsigned int i; float f; } c; c.i = v & 0xffff0000u; return c.f;
}

// ---------------- Kernel 1: Y precompute (exact R4 version) -------------------
// grid = 4*ceil(NPE/8); block=256 (thread = col o). 8 rows/block.
// pe loads block-uniform -> scalar; W loads coalesced (lane o consecutive).
__global__ __launch_bounds__(256) void precompute_Y(
        const float* __restrict__ pe,
        const float* __restrict__ W,
        const float* __restrict__ bias,
        __hip_bfloat16* __restrict__ Y,
        int NPE) {
    const int H = 256;
    const int ntile = (NPE + 7) >> 3;
    const int k  = blockIdx.x / ntile;
    const int r0 = (blockIdx.x % ntile) << 3;
    const int o  = threadIdx.x;
    const float* __restrict__ Wk = W + (size_t)k * H * H;

    int rows[8];
#pragma unroll
    for (int r = 0; r < 8; ++r) rows[r] = min(r0 + r, NPE - 1);

    float acc[8];
#pragma unroll
    for (int r = 0; r < 8; ++r) acc[r] = 0.f;

#pragma unroll 2
    for (int h = 0; h < 256; h += 4) {
        const float w0 = Wk[(h + 0) * H + o];
        const float w1 = Wk[(h + 1) * H + o];
        const float w2 = Wk[(h + 2) * H + o];
        const float w3 = Wk[(h + 3) * H + o];
#pragma unroll
        for (int r = 0; r < 8; ++r) {
            const f32x4 p = *reinterpret_cast<const f32x4*>(&pe[rows[r] * H + h]);
            acc[r] += p.x * w0 + p.y * w1 + p.z * w2 + p.w * w3;
        }
    }
    const float bv = (k == 0) ? bias[o] : 0.f;
#pragma unroll
    for (int r = 0; r < 8; ++r) {
        const int rr = r0 + r;
        if (rr < NPE)
            Y[((size_t)k * NPE + rr) * H + o] = __float2bfloat16(acc[r] + bv);
    }
}

// ---------------- Kernel 2: pipelined gather-add + lrelu ----------------------
// block = 256 thr = 4 waves; block covers (bb, i, 64 j's); wave w owns 16 j's.
// Per j: 4 x uint2 row loads (512 B/wave/table) + one 1 KB coalesced NT store.
// unroll 4 => 4 independent chains in flight; si/ei hoisted out of the loop.
__global__ __launch_bounds__(256) void gather_pipe(
        const int* __restrict__ pos_s,
        const int* __restrict__ pos_e,
        const __hip_bfloat16* __restrict__ Y,
        float* __restrict__ out,
        int S, int ML, int NPE) {
    const int t  = threadIdx.x;
    const int w  = t >> 6;
    const int ln = t & 63;
    const int nq = S >> 6;                 // 64-j groups per row

    const int q  = blockIdx.x % nq;
    const int i  = (blockIdx.x / nq) % S;
    const int bb = blockIdx.x / (nq * S);
    const int jb = (q << 6) + (w << 4);    // this wave's first j

    const int si = pos_s[bb * S + i];
    const int ei = pos_e[bb * S + i];
    // row = base - sj (or - ej); bases fold k*NPE + ML + si/ei.
    const int base0 = 0 * NPE + si + ML;
    const int base1 = 1 * NPE + si + ML;
    const int base2 = 2 * NPE + ei + ML;
    const int base3 = 3 * NPE + ei + ML;

    const uint2* __restrict__ Yv = reinterpret_cast<const uint2*>(Y);
    const int* __restrict__ ps = pos_s + bb * S + jb;
    const int* __restrict__ pq = pos_e + bb * S + jb;
    f32x4* __restrict__ ov = reinterpret_cast<f32x4*>(out) +
                             ((((size_t)bb * S + i) * S + jb) << 6) + ln;

#pragma unroll 4
    for (int n = 0; n < 16; ++n) {
        const int sj = ps[n];
        const int ej = pq[n];
        const uint2 u0 = Yv[((size_t)(base0 - sj) << 6) + ln];
        const uint2 u1 = Yv[((size_t)(base1 - ej) << 6) + ln];
        const uint2 u2 = Yv[((size_t)(base2 - sj) << 6) + ln];
        const uint2 u3 = Yv[((size_t)(base3 - ej) << 6) + ln];

        f32x4 v;
        v.x = lrelu(bflo(u0.x) + bflo(u1.x) + bflo(u2.x) + bflo(u3.x));
        v.y = lrelu(bfhi(u0.x) + bfhi(u1.x) + bfhi(u2.x) + bfhi(u3.x));
        v.z = lrelu(bflo(u0.y) + bflo(u1.y) + bflo(u2.y) + bflo(u3.y));
        v.w = lrelu(bfhi(u0.y) + bfhi(u1.y) + bfhi(u2.y) + bfhi(u3.y));

        __builtin_nontemporal_store(v, ov + (n << 6));
    }
}

// ---------------- Fallback: direct compute (ws too small / odd shapes) --------
__global__ void direct_kernel(const int* __restrict__ pos_s,
                              const int* __restrict__ pos_e,
                              const float* __restrict__ pe,
                              const float* __restrict__ W,
                              const float* __restrict__ bias,
                              float* __restrict__ out,
                              int B, int S, int H, int ML) {
    const int blk = blockIdx.x;
    const int j   = blk % S;
    const int i   = (blk / S) % S;
    const int bb  = blk / (S * S);
    const int o   = threadIdx.x;

    const int si = pos_s[bb * S + i];
    const int ei = pos_e[bb * S + i];
    const int sj = pos_s[bb * S + j];
    const int ej = pos_e[bb * S + j];

    const int rss = si - sj + ML;
    const int rse = si - ej + ML;
    const int res = ei - sj + ML;
    const int ree = ei - ej + ML;

    float acc = bias[o];
    for (int h = 0; h < H; ++h) {
        acc += pe[rss * H + h] * W[(0 * H + h) * H + o];
        acc += pe[rse * H + h] * W[(1 * H + h) * H + o];
        acc += pe[res * H + h] * W[(2 * H + h) * H + o];
        acc += pe[ree * H + h] * W[(3 * H + h) * H + o];
    }
    out[(((size_t)bb * S + i) * S + j) * H + o] = lrelu(acc);
}

extern "C" void kernel_launch(void* const* d_in, const int* in_sizes, int n_in,
                              void* d_out, int out_size, void* d_ws, size_t ws_size,
                              hipStream_t stream) {
    const int*   pos_s = (const int*)d_in[0];
    const int*   pos_e = (const int*)d_in[1];
    const float* pe    = (const float*)d_in[2];
    const float* W     = (const float*)d_in[3];
    const float* bias  = (const float*)d_in[4];
    float*       out   = (float*)d_out;

    const int H   = in_sizes[4];                 // 256
    const int NPE = in_sizes[2] / H;             // 1025
    const int ML  = (NPE - 1) / 2;               // 512
    const int BS  = in_sizes[0];                 // B*S
    const int S   = (int)((long long)out_size / ((long long)BS * H)); // 256
    const int B   = BS / S;                      // 2

    const size_t ybytes = (size_t)4 * NPE * 256 * sizeof(__hip_bfloat16); // 2.1 MB

    if (H == 256 && (S & 63) == 0 && ws_size >= ybytes) {
        __hip_bfloat16* Y = (__hip_bfloat16*)d_ws;
        const int ntile = (NPE + 7) >> 3;
        precompute_Y<<<4 * ntile, 256, 0, stream>>>(pe, W, bias, Y, NPE);
        const int nblk = B * S * (S >> 6);
        gather_pipe<<<nblk, 256, 0, stream>>>(pos_s, pos_e, Y, out, S, ML, NPE);
    } else {
        direct_kernel<<<B * S * S, H, 0, stream>>>(pos_s, pos_e, pe, W, bias, out,
                                                   B, S, H, ML);
    }
}